// Round 1
// baseline (426.490 us; speedup 1.0000x reference)
//
#include <hip/hip_runtime.h>
#include <math.h>

#define TT 512
#define BB 512
#define FF 14
#define H1 32
#define H2 64
#define NR 16               // rows (batch cols) per block
#define NBLK (BB / NR)      // 32 blocks

typedef _Float16 half8   __attribute__((ext_vector_type(8)));
typedef float    float4v __attribute__((ext_vector_type(4)));

typedef __attribute__((address_space(1))) void av1_t;   // global
typedef __attribute__((address_space(3))) void av3_t;   // LDS

__device__ __forceinline__ float rcpf_(float x) { return __builtin_amdgcn_rcpf(x); }
__device__ __forceinline__ float sigmoidf_(float x) { return rcpf_(1.0f + __expf(-x)); }
__device__ __forceinline__ float tanhf_(float x) {
    float e = __expf(-2.0f * fabsf(x));
    float t = (1.0f - e) * rcpf_(1.0f + e);
    return copysignf(t, x);
}
__device__ __forceinline__ float4v mfma16(half8 a, half8 b, float4v c) {
    return __builtin_amdgcn_mfma_f32_16x16x32_f16(a, b, c, 0, 0, 0);
}

// B-fragment element (k, n): lane = n + 16*((k&31)>>3 & 3), dword = (k&31)>>1 & 3,
// half = k&1, slab = k>>5.  Returns HALF-index into (unsigned*) frag area.
__device__ __forceinline__ int bfrag_off(int k, int n) {
    const int slab = k >> 5, k5 = k & 31;
    const int dl = n + 16 * ((k5 >> 3) & 3);
    const int dw = (k5 >> 1) & 3;
    return ((slab * 256 + dl * 4 + dw) << 1) | (k5 & 1);
}

// R17: kill the per-step vmcnt(0) drain. __syncthreads() forces the x global
// load to COMPLETE inside the same step (300-600 cy of exposed HBM/L3 latency
// every iteration, FETCH=7.7MB ~ half of x from HBM). Replaced with raw
// s_barrier + lgkmcnt(0)-only (m201/m214 pattern); x moved from LDS staging to
// per-lane register B-fragments prefetched 2 steps deep (loads now span
// barriers); s1f eliminated (layer-1 split into x-MFMA + h1-MFMA, h1 operand
// shared with layer-2's s2f slab 0 -> -2KB/wave/step LDS reads, h1 written
// once, x-staging scatter writes + their bank conflicts gone, wave-0 barrier
// imbalance gone); global_load_lds touch 16 steps ahead warms L2 without any
// register consumer (never waited on inside the loop).
__global__ __launch_bounds__(512)
__attribute__((amdgpu_waves_per_eu(2, 2)))
void lstm3_kernel(
    const float* __restrict__ x,
    const float* __restrict__ Wih1, const float* __restrict__ Whh1,
    const float* __restrict__ bih1, const float* __restrict__ bhh1,
    const float* __restrict__ Wih2, const float* __restrict__ Whh2,
    const float* __restrict__ bih2, const float* __restrict__ bhh2,
    const float* __restrict__ Wfc1, const float* __restrict__ bfc1,
    const float* __restrict__ Wfc2, const float* __restrict__ bfc2,
    const float* __restrict__ Wfc,  const float* __restrict__ bfc,
    float* __restrict__ out)
{
    const int row0 = blockIdx.x * NR;
    const int l    = threadIdx.x;
    const int lane = l & 63;
    const int w    = l >> 6;        // wave 0..7
    const int n    = lane & 15;     // batch col within block
    const int quad = lane >> 4;

    // s2f: K=96 (3 slabs): [h1 k=0..31 | h2 k=32..95], double-buffered by parity.
    __shared__ __align__(16) unsigned s2f[2][3 * 256];
    __shared__ _Float16 h2plain[NR][H2];
    __shared__ float mlp1[NR][8];
    __shared__ float mlp2[NR][8];
    __shared__ float pfl[16];       // prefetch-touch dump, never read

    // ---------------- layer-2 A-fragments + bias (unchanged) ----------------
    half8 a2[2][3];
    float4v bias2[2];
    #pragma unroll
    for (int tt = 0; tt < 2; ++tt) {
        const int T = 2 * w + tt;
        const int m = T * 16 + n;
        const int row = (m & 3) * 64 + (m >> 2);   // orig gate row (i|f|g|o)
        #pragma unroll
        for (int s = 0; s < 3; ++s) {
            const int k0 = s * 32 + quad * 8;
            half8 a;
            if (k0 < H1) {
                #pragma unroll
                for (int j = 0; j < 8; ++j) a[j] = (_Float16)Wih2[row * H1 + k0 + j];
            } else {
                #pragma unroll
                for (int j = 0; j < 8; ++j) a[j] = (_Float16)Whh2[row * H2 + (k0 - H1) + j];
            }
            a2[tt][s] = a;
        }
        const int u = T * 4 + quad;
        #pragma unroll
        for (int r = 0; r < 4; ++r) {
            const int br = r * 64 + u;
            bias2[tt][r] = bih2[br] + bhh2[br];
        }
    }

    // ---------------- layer-1 A-fragments: a1x (k>=FF zero) + a1h ----------------
    half8 a1x, a1h;
    float4v bias1;
    {
        const int m = w * 16 + n;
        const int row = (m & 3) * 32 + (m >> 2);   // 0..127
        #pragma unroll
        for (int j = 0; j < 8; ++j) {
            const int k = quad * 8 + j;            // 0..31
            a1x[j] = (_Float16)((k < FF) ? Wih1[row * FF + k] : 0.0f);
            a1h[j] = (_Float16)Whh1[row * H1 + k];
        }
        const int u1_ = w * 4 + quad;
        #pragma unroll
        for (int r = 0; r < 4; ++r) {
            const int br = r * 32 + u1_;
            bias1[r] = bih1[br] + bhh1[br];
        }
    }

    // ---------------- write offsets (half-indices into s2f) ----------------
    const int u1   = w * 4 + quad;
    const int offB = bfrag_off(u1, n);              // h1 -> s2f slab0
    int off2[2];
    #pragma unroll
    for (int tt = 0; tt < 2; ++tt)
        off2[tt] = bfrag_off(32 + (2 * w + tt) * 4 + quad, n);   // h2 -> s2f slabs 1,2

    // ---------------- per-lane x register B-frag addressing ----------------
    // lane (quad,n) holds B-frag k = 8*quad .. 8*quad+7. quads 2,3 mirror 0,1
    // (their A-weights are zero); features >= FF also have zero A-weights, so
    // duplicated/garbage-but-finite loads there are harmless. All float2 loads
    // are 8B aligned ((14*row + even)*4).
    const int b1q  = quad & 1;
    const int xrow = (row0 + n) * FF;
    const int xo0 = 8 * b1q;
    const int xo1 = 8 * b1q + 2;
    const int xo2 = 8 * b1q + 4;
    const int xo3 = 6 * b1q + 6;        // b=0 -> f6,f7 ; b=1 -> f12,f13 (dup, zero wt)

    float c1r = 0.0f;                   // layer-1 cell state for (u1, n)
    float2 xr0[4], xr1[4];              // x(t) raw, ping-pong, 2-step prefetch depth

    for (int z = l; z < 2 * 3 * 256; z += 512) ((unsigned*)s2f)[z] = 0u;

    {
        const float* xp = x + xrow;                  // t = 0 -> xr0
        xr0[0] = *(const float2*)(xp + xo0);
        xr0[1] = *(const float2*)(xp + xo1);
        xr0[2] = *(const float2*)(xp + xo2);
        xr0[3] = *(const float2*)(xp + xo3);
        const float* xq = x + BB * FF + xrow;        // t = 1 -> xr1
        xr1[0] = *(const float2*)(xq + xo0);
        xr1[1] = *(const float2*)(xq + xo1);
        xr1[2] = *(const float2*)(xq + xo2);
        xr1[3] = *(const float2*)(xq + xo3);
    }
    __syncthreads();   // one full drain before the loop (weights + xr0/xr1)

// One recurrence step: layer-1(i) + layer-2(i-1). CP_/RP_ are compile-time
// s2f parities. Trailing sync is lgkm-only: global loads stay in flight.
#define LSTM_STEP(i_, CP_, RP_, XR_) do {                                          \
        const half8 tb0 = *(const half8*)(s2f[RP_] + lane * 4);                    \
        const half8 tb1 = *(const half8*)(s2f[RP_] + 256 + lane * 4);              \
        const half8 tb2 = *(const half8*)(s2f[RP_] + 512 + lane * 4);              \
        half8 xb;                                                                  \
        xb[0] = (_Float16)XR_[0].x; xb[1] = (_Float16)XR_[0].y;                    \
        xb[2] = (_Float16)XR_[1].x; xb[3] = (_Float16)XR_[1].y;                    \
        xb[4] = (_Float16)XR_[2].x; xb[5] = (_Float16)XR_[2].y;                    \
        xb[6] = (_Float16)XR_[3].x; xb[7] = (_Float16)XR_[3].y;                    \
        { int tn_ = (i_) + 2; if (tn_ > TT - 1) tn_ = TT - 1;                      \
          const float* xp_ = x + tn_ * (BB * FF) + xrow;                           \
          XR_[0] = *(const float2*)(xp_ + xo0);                                    \
          XR_[1] = *(const float2*)(xp_ + xo1);                                    \
          XR_[2] = *(const float2*)(xp_ + xo2);                                    \
          XR_[3] = *(const float2*)(xp_ + xo3); }                                  \
        if (l < 14) {                                                              \
            int tp_ = (i_) + 16; if (tp_ > TT - 1) tp_ = TT - 1;                   \
            __builtin_amdgcn_global_load_lds(                                      \
                (av1_t*)(x + (size_t)tp_ * (BB * FF) + row0 * FF + l * 16),        \
                (av3_t*)&pfl[0], 4, 0, 0);                                         \
        }                                                                          \
        float4v acc1 = mfma16(a1x, xb, bias1);                                     \
        acc1 = mfma16(a1h, tb0, acc1);                                             \
        const float cn1 = sigmoidf_(acc1[1]) * c1r                                 \
                        + sigmoidf_(acc1[0]) * tanhf_(acc1[2]);                    \
        c1r = cn1;                                                                 \
        ((_Float16*)s2f[CP_])[offB] = (_Float16)(sigmoidf_(acc1[3]) * tanhf_(cn1));\
        _Pragma("unroll")                                                          \
        for (int tt = 0; tt < 2; ++tt) {                                           \
            float4v acc = bias2[tt];                                               \
            acc = mfma16(a2[tt][0], tb0, acc);                                     \
            acc = mfma16(a2[tt][1], tb1, acc);                                     \
            acc = mfma16(a2[tt][2], tb2, acc);                                     \
            const float cn = sigmoidf_(acc[0]) * tanhf_(acc[2]);                   \
            const float h  = sigmoidf_(acc[3]) * tanhf_(cn);                       \
            ((_Float16*)s2f[CP_])[off2[tt]] = (_Float16)h;                         \
        }                                                                          \
        asm volatile("s_waitcnt lgkmcnt(0)" ::: "memory");                         \
        __builtin_amdgcn_s_barrier();                                              \
        asm volatile("" ::: "memory");                                             \
    } while (0)

    // ---------------- i = 0 (peeled): layer-1 only, h1(-1)=0, c1=0 ----------------
    {
        half8 xb;
        xb[0] = (_Float16)xr0[0].x; xb[1] = (_Float16)xr0[0].y;
        xb[2] = (_Float16)xr0[1].x; xb[3] = (_Float16)xr0[1].y;
        xb[4] = (_Float16)xr0[2].x; xb[5] = (_Float16)xr0[2].y;
        xb[6] = (_Float16)xr0[3].x; xb[7] = (_Float16)xr0[3].y;
        {   const float* xp_ = x + 2 * (BB * FF) + xrow;     // reload xr0 <- t=2
            xr0[0] = *(const float2*)(xp_ + xo0);
            xr0[1] = *(const float2*)(xp_ + xo1);
            xr0[2] = *(const float2*)(xp_ + xo2);
            xr0[3] = *(const float2*)(xp_ + xo3); }
        if (l < 14) {
            __builtin_amdgcn_global_load_lds(
                (av1_t*)(x + (size_t)16 * (BB * FF) + row0 * FF + l * 16),
                (av3_t*)&pfl[0], 4, 0, 0);
        }
        float4v acc1 = mfma16(a1x, xb, bias1);
        const float cn1 = sigmoidf_(acc1[0]) * tanhf_(acc1[2]);  // f-term * c1r(=0) == 0
        c1r = cn1;
        ((_Float16*)s2f[0])[offB] = (_Float16)(sigmoidf_(acc1[3]) * tanhf_(cn1));
        asm volatile("s_waitcnt lgkmcnt(0)" ::: "memory");
        __builtin_amdgcn_s_barrier();
        asm volatile("" ::: "memory");
    }

    // ---------------- steady loop: i = 1 .. 510 (pairs), tail i = 511 ----------------
    #pragma unroll 1
    for (int ii = 0; ii < 255; ++ii) {
        const int i0 = 2 * ii + 1;
        LSTM_STEP(i0,     1, 0, xr1);     // odd i:  cp=1, rp=0
        LSTM_STEP(i0 + 1, 0, 1, xr0);     // even i: cp=0, rp=1
    }
    LSTM_STEP(511, 1, 0, xr1);

    // ---------------- final layer-2 (step 511) -> h2plain ----------------
    {
        const half8 tb0 = *(const half8*)(s2f[1] + lane * 4);
        const half8 tb1 = *(const half8*)(s2f[1] + 256 + lane * 4);
        const half8 tb2 = *(const half8*)(s2f[1] + 512 + lane * 4);
        #pragma unroll
        for (int tt = 0; tt < 2; ++tt) {
            float4v acc = bias2[tt];
            acc = mfma16(a2[tt][0], tb0, acc);
            acc = mfma16(a2[tt][1], tb1, acc);
            acc = mfma16(a2[tt][2], tb2, acc);
            const float cn = sigmoidf_(acc[0]) * tanhf_(acc[2]);
            const float h  = sigmoidf_(acc[3]) * tanhf_(cn);
            h2plain[n][(2 * w + tt) * 4 + quad] = (_Float16)h;
        }
        __syncthreads();
    }

    // ---------------- MLP head (16 rows) ----------------
    if (l < NR * 8) {
        const int rr = l >> 3, j = l & 7;
        float a = bfc1[j];
        #pragma unroll
        for (int k = 0; k < H2; ++k)
            a = fmaf(fmaxf((float)h2plain[rr][k], 0.0f), Wfc1[j * H2 + k], a);
        mlp1[rr][j] = fmaxf(a, 0.0f);
    }
    __syncthreads();
    if (l < NR * 8) {
        const int rr = l >> 3, j = l & 7;
        float a = bfc2[j];
        #pragma unroll
        for (int k = 0; k < 8; ++k) a = fmaf(mlp1[rr][k], Wfc2[j * 8 + k], a);
        mlp2[rr][j] = fmaxf(a, 0.0f);
    }
    __syncthreads();
    if (l < NR) {
        float a = bfc[0];
        #pragma unroll
        for (int k = 0; k < 8; ++k) a = fmaf(mlp2[l][k], Wfc[k], a);
        out[row0 + l] = a;
    }
}

extern "C" void kernel_launch(void* const* d_in, const int* in_sizes, int n_in,
                              void* d_out, int out_size, void* d_ws, size_t ws_size,
                              hipStream_t stream) {
    const float* x    = (const float*)d_in[0];
    const float* Wih1 = (const float*)d_in[1];
    const float* Whh1 = (const float*)d_in[2];
    const float* bih1 = (const float*)d_in[3];
    const float* bhh1 = (const float*)d_in[4];
    const float* Wih2 = (const float*)d_in[5];
    const float* Whh2 = (const float*)d_in[6];
    const float* bih2 = (const float*)d_in[7];
    const float* bhh2 = (const float*)d_in[8];
    const float* Wfc1 = (const float*)d_in[9];
    const float* bfc1 = (const float*)d_in[10];
    const float* Wfc2 = (const float*)d_in[11];
    const float* bfc2 = (const float*)d_in[12];
    const float* Wfc  = (const float*)d_in[13];
    const float* bfc  = (const float*)d_in[14];
    float* out = (float*)d_out;

    lstm3_kernel<<<dim3(NBLK), dim3(512), 0, stream>>>(
        x, Wih1, Whh1, bih1, bhh1, Wih2, Whh2, bih2, bhh2,
        Wfc1, bfc1, Wfc2, bfc2, Wfc, bfc, out);
}

// Round 2
// 406.782 us; speedup vs baseline: 1.0484x; 1.0484x over previous
//
#include <hip/hip_runtime.h>
#include <math.h>

#define TT 512
#define BB 512
#define FF 14
#define H1 32
#define H2 64
#define NR 16               // rows (batch cols) per block
#define NBLK (BB / NR)      // 32 blocks

typedef _Float16 half8   __attribute__((ext_vector_type(8)));
typedef float    float4v __attribute__((ext_vector_type(4)));

typedef __attribute__((address_space(1))) void av1_t;   // global
typedef __attribute__((address_space(3))) void av3_t;   // LDS

__device__ __forceinline__ float rcpf_(float x) { return __builtin_amdgcn_rcpf(x); }
__device__ __forceinline__ float sigmoidf_(float x) { return rcpf_(1.0f + __expf(-x)); }
__device__ __forceinline__ float tanhf_(float x) {
    float e = __expf(-2.0f * fabsf(x));
    float t = (1.0f - e) * rcpf_(1.0f + e);
    return copysignf(t, x);
}
__device__ __forceinline__ float4v mfma16(half8 a, half8 b, float4v c) {
    return __builtin_amdgcn_mfma_f32_16x16x32_f16(a, b, c, 0, 0, 0);
}

// B-fragment element (k, n): lane = n + 16*((k&31)>>3 & 3), dword = (k&31)>>1 & 3,
// half = k&1, slab = k>>5.  Returns HALF-index into (unsigned*) frag area.
__device__ __forceinline__ int bfrag_off(int k, int n) {
    const int slab = k >> 5, k5 = k & 31;
    const int dl = n + 16 * ((k5 >> 3) & 3);
    const int dw = (k5 >> 1) & 3;
    return ((slab * 256 + dl * 4 + dw) << 1) | (k5 & 1);
}

// ============================================================================
// R18: precompute xg = x @ Wih1^T + bih1 + bhh1 outside the recurrence (same
// trick as the JAX reference). Layout is chosen so the recurrence kernel reads
// its layer-1 C-fragment (4 floats: gates i,f,g,o of its unit) as ONE coalesced
// dwordx4 per lane: xg[t][blk][l] (float4), l = thread id in the main kernel.
// This kills R17's 4 scattered float2 loads/lane/step + 8 cvts + 1 MFMA.
// ============================================================================
__global__ __launch_bounds__(512)
void xg_precompute(const float* __restrict__ x,
                   const float* __restrict__ Wih1,
                   const float* __restrict__ bih1,
                   const float* __restrict__ bhh1,
                   float* __restrict__ xg)
{
    const int t    = blockIdx.x;
    const int l    = threadIdx.x;
    const int lane = l & 63;
    const int w    = l >> 6;
    const int n    = lane & 15;
    const int quad = lane >> 4;
    const int u1   = w * 4 + quad;

    float wr[4][FF];
    float bs[4];
    #pragma unroll
    for (int r = 0; r < 4; ++r) {
        const int row = r * 32 + u1;          // gate rows i|f|g|o for unit u1
        #pragma unroll
        for (int f = 0; f < FF; ++f) wr[r][f] = Wih1[row * FF + f];
        bs[r] = bih1[row] + bhh1[row];
    }

    float4v* og = (float4v*)xg + (size_t)t * (NBLK * 512) + l;
    for (int blk = 0; blk < NBLK; ++blk) {
        const float* xp = x + ((size_t)t * BB + blk * NR + n) * FF;
        float xv[FF];
        #pragma unroll
        for (int e = 0; e < 7; ++e) {                 // row*56B is 8B-aligned
            const float2 v = *(const float2*)(xp + 2 * e);
            xv[2 * e] = v.x; xv[2 * e + 1] = v.y;
        }
        float4v o;
        #pragma unroll
        for (int r = 0; r < 4; ++r) {
            float a = bs[r];
            #pragma unroll
            for (int f = 0; f < FF; ++f) a = fmaf(xv[f], wr[r][f], a);
            o[r] = a;
        }
        og[(size_t)blk * 512] = o;
    }
}

// ============================================================================
// R18 main recurrence. Per step: 1 coalesced float4 xg load (depth-4 register
// prefetch, spans the lgkm-only barriers), 3 ds_read_b128, 1 layer-1 MFMA,
// 6 layer-2 MFMAs, activations, 3 ds_write_b16, lgkmcnt(0)+s_barrier.
// ============================================================================
#define XGIDX(t_) ((size_t)(t_) * (NBLK * 512))

__global__ __launch_bounds__(512)
__attribute__((amdgpu_waves_per_eu(2, 2)))
void lstm3_xg(
    const float* __restrict__ xg,
    const float* __restrict__ Wih2, const float* __restrict__ Whh1,
    const float* __restrict__ Whh2,
    const float* __restrict__ bih2, const float* __restrict__ bhh2,
    const float* __restrict__ Wfc1, const float* __restrict__ bfc1,
    const float* __restrict__ Wfc2, const float* __restrict__ bfc2,
    const float* __restrict__ Wfc,  const float* __restrict__ bfc,
    float* __restrict__ out)
{
    const int row0 = blockIdx.x * NR;
    const int l    = threadIdx.x;
    const int lane = l & 63;
    const int w    = l >> 6;        // wave 0..7
    const int n    = lane & 15;     // batch col within block
    const int quad = lane >> 4;

    // s2f: K=96 (3 slabs): [h1 k=0..31 | h2 k=32..95], double-buffered by parity.
    __shared__ __align__(16) unsigned s2f[2][3 * 256];
    __shared__ _Float16 h2plain[NR][H2];
    __shared__ float mlp1[NR][8];
    __shared__ float mlp2[NR][8];

    // ---------------- layer-2 A-fragments + bias ----------------
    half8 a2[2][3];
    float4v bias2[2];
    #pragma unroll
    for (int tt = 0; tt < 2; ++tt) {
        const int T = 2 * w + tt;
        const int m = T * 16 + n;
        const int row = (m & 3) * 64 + (m >> 2);   // orig gate row (i|f|g|o)
        #pragma unroll
        for (int s = 0; s < 3; ++s) {
            const int k0 = s * 32 + quad * 8;
            half8 a;
            if (k0 < H1) {
                #pragma unroll
                for (int j = 0; j < 8; ++j) a[j] = (_Float16)Wih2[row * H1 + k0 + j];
            } else {
                #pragma unroll
                for (int j = 0; j < 8; ++j) a[j] = (_Float16)Whh2[row * H2 + (k0 - H1) + j];
            }
            a2[tt][s] = a;
        }
        const int u = T * 4 + quad;
        #pragma unroll
        for (int r = 0; r < 4; ++r) {
            const int br = r * 64 + u;
            bias2[tt][r] = bih2[br] + bhh2[br];
        }
    }

    // ---------------- layer-1 recurrent A-fragment (x part precomputed) ----
    half8 a1h;
    {
        const int m = w * 16 + n;
        const int row = (m & 3) * 32 + (m >> 2);   // 0..127
        #pragma unroll
        for (int j = 0; j < 8; ++j)
            a1h[j] = (_Float16)Whh1[row * H1 + quad * 8 + j];
    }

    // ---------------- write offsets (half-indices into s2f) ----------------
    const int u1   = w * 4 + quad;
    const int offB = bfrag_off(u1, n);              // h1 -> s2f slab0
    int off2[2];
    #pragma unroll
    for (int tt = 0; tt < 2; ++tt)
        off2[tt] = bfrag_off(32 + (2 * w + tt) * 4 + quad, n);   // h2 -> slabs 1,2

    const float4v* xgbase = (const float4v*)xg + (size_t)blockIdx.x * 512 + l;

    float c1r = 0.0f;                   // layer-1 cell state for (u1, n)

    for (int z = l; z < 2 * 3 * 256; z += 512) ((unsigned*)s2f)[z] = 0u;

    // prologue: xg(0) for the peel, xg(1..4) into the depth-4 ring
    float4v xg0 = xgbase[XGIDX(0)];
    float4v xgA = xgbase[XGIDX(1)];
    float4v xgB = xgbase[XGIDX(2)];
    float4v xgC = xgbase[XGIDX(3)];
    float4v xgD = xgbase[XGIDX(4)];
    __syncthreads();   // one full drain before the loop

// One recurrence step: layer-1(i) + layer-2(i-1). CP_/RP_ compile-time
// parities. Trailing sync is lgkm-only: xg loads stay in flight across it.
#define LSTM_STEP(i_, CP_, RP_, XG_) do {                                          \
        const float4v cin_ = XG_;   /* waits on load issued 4 bodies ago */        \
        { int tn_ = (i_) + 4; if (tn_ > TT - 1) tn_ = TT - 1;                      \
          XG_ = xgbase[XGIDX(tn_)]; }                                              \
        const half8 tb0 = *(const half8*)(s2f[RP_] + lane * 4);                    \
        const half8 tb1 = *(const half8*)(s2f[RP_] + 256 + lane * 4);              \
        const half8 tb2 = *(const half8*)(s2f[RP_] + 512 + lane * 4);              \
        float4v acc1 = mfma16(a1h, tb0, cin_);                                     \
        const float cn1 = sigmoidf_(acc1[1]) * c1r                                 \
                        + sigmoidf_(acc1[0]) * tanhf_(acc1[2]);                    \
        c1r = cn1;                                                                 \
        ((_Float16*)s2f[CP_])[offB] = (_Float16)(sigmoidf_(acc1[3]) * tanhf_(cn1));\
        _Pragma("unroll")                                                          \
        for (int tt = 0; tt < 2; ++tt) {                                           \
            float4v acc = bias2[tt];                                               \
            acc = mfma16(a2[tt][0], tb0, acc);                                     \
            acc = mfma16(a2[tt][1], tb1, acc);                                     \
            acc = mfma16(a2[tt][2], tb2, acc);                                     \
            const float cn = sigmoidf_(acc[0]) * tanhf_(acc[2]);                   \
            const float h  = sigmoidf_(acc[3]) * tanhf_(cn);                       \
            ((_Float16*)s2f[CP_])[off2[tt]] = (_Float16)h;                         \
        }                                                                          \
        asm volatile("s_waitcnt lgkmcnt(0)" ::: "memory");                         \
        __builtin_amdgcn_s_barrier();                                              \
        asm volatile("" ::: "memory");                                             \
    } while (0)

    // ---------------- i = 0 (peeled): layer-1 only, h1(-1)=0, c1=0 ----------
    {
        const float4v acc1 = xg0;                    // C = xg(0), no MFMA needed
        const float cn1 = sigmoidf_(acc1[0]) * tanhf_(acc1[2]);  // f*c1r(=0)==0
        c1r = cn1;
        ((_Float16*)s2f[0])[offB] = (_Float16)(sigmoidf_(acc1[3]) * tanhf_(cn1));
        asm volatile("s_waitcnt lgkmcnt(0)" ::: "memory");
        __builtin_amdgcn_s_barrier();
        asm volatile("" ::: "memory");
    }

    // ---------------- steady loop: i = 1 .. 508 (quads), tail 509..511 ------
    #pragma unroll 1
    for (int ii = 0; ii < 127; ++ii) {
        const int i0 = 4 * ii + 1;
        LSTM_STEP(i0,     1, 0, xgA);
        LSTM_STEP(i0 + 1, 0, 1, xgB);
        LSTM_STEP(i0 + 2, 1, 0, xgC);
        LSTM_STEP(i0 + 3, 0, 1, xgD);
    }
    LSTM_STEP(509, 1, 0, xgA);
    LSTM_STEP(510, 0, 1, xgB);
    LSTM_STEP(511, 1, 0, xgC);

    // ---------------- final layer-2 (step 511) -> h2plain ----------------
    {
        const half8 tb0 = *(const half8*)(s2f[1] + lane * 4);
        const half8 tb1 = *(const half8*)(s2f[1] + 256 + lane * 4);
        const half8 tb2 = *(const half8*)(s2f[1] + 512 + lane * 4);
        #pragma unroll
        for (int tt = 0; tt < 2; ++tt) {
            float4v acc = bias2[tt];
            acc = mfma16(a2[tt][0], tb0, acc);
            acc = mfma16(a2[tt][1], tb1, acc);
            acc = mfma16(a2[tt][2], tb2, acc);
            const float cn = sigmoidf_(acc[0]) * tanhf_(acc[2]);
            const float h  = sigmoidf_(acc[3]) * tanhf_(cn);
            h2plain[n][(2 * w + tt) * 4 + quad] = (_Float16)h;
        }
        __syncthreads();
    }

    // ---------------- MLP head (16 rows) ----------------
    if (l < NR * 8) {
        const int rr = l >> 3, j = l & 7;
        float a = bfc1[j];
        #pragma unroll
        for (int k = 0; k < H2; ++k)
            a = fmaf(fmaxf((float)h2plain[rr][k], 0.0f), Wfc1[j * H2 + k], a);
        mlp1[rr][j] = fmaxf(a, 0.0f);
    }
    __syncthreads();
    if (l < NR * 8) {
        const int rr = l >> 3, j = l & 7;
        float a = bfc2[j];
        #pragma unroll
        for (int k = 0; k < 8; ++k) a = fmaf(mlp1[rr][k], Wfc2[j * 8 + k], a);
        mlp2[rr][j] = fmaxf(a, 0.0f);
    }
    __syncthreads();
    if (l < NR) {
        float a = bfc[0];
        #pragma unroll
        for (int k = 0; k < 8; ++k) a = fmaf(mlp2[l][k], Wfc[k], a);
        out[row0 + l] = a;
    }
#undef LSTM_STEP
}

// ============================================================================
// Fallback (R17 structure) if the workspace can't hold xg.
// ============================================================================
__global__ __launch_bounds__(512)
__attribute__((amdgpu_waves_per_eu(2, 2)))
void lstm3_kernel(
    const float* __restrict__ x,
    const float* __restrict__ Wih1, const float* __restrict__ Whh1,
    const float* __restrict__ bih1, const float* __restrict__ bhh1,
    const float* __restrict__ Wih2, const float* __restrict__ Whh2,
    const float* __restrict__ bih2, const float* __restrict__ bhh2,
    const float* __restrict__ Wfc1, const float* __restrict__ bfc1,
    const float* __restrict__ Wfc2, const float* __restrict__ bfc2,
    const float* __restrict__ Wfc,  const float* __restrict__ bfc,
    float* __restrict__ out)
{
    const int row0 = blockIdx.x * NR;
    const int l    = threadIdx.x;
    const int lane = l & 63;
    const int w    = l >> 6;
    const int n    = lane & 15;
    const int quad = lane >> 4;

    __shared__ __align__(16) unsigned s2f[2][3 * 256];
    __shared__ _Float16 h2plain[NR][H2];
    __shared__ float mlp1[NR][8];
    __shared__ float mlp2[NR][8];
    __shared__ float pfl[16];

    half8 a2[2][3];
    float4v bias2[2];
    #pragma unroll
    for (int tt = 0; tt < 2; ++tt) {
        const int T = 2 * w + tt;
        const int m = T * 16 + n;
        const int row = (m & 3) * 64 + (m >> 2);
        #pragma unroll
        for (int s = 0; s < 3; ++s) {
            const int k0 = s * 32 + quad * 8;
            half8 a;
            if (k0 < H1) {
                #pragma unroll
                for (int j = 0; j < 8; ++j) a[j] = (_Float16)Wih2[row * H1 + k0 + j];
            } else {
                #pragma unroll
                for (int j = 0; j < 8; ++j) a[j] = (_Float16)Whh2[row * H2 + (k0 - H1) + j];
            }
            a2[tt][s] = a;
        }
        const int u = T * 4 + quad;
        #pragma unroll
        for (int r = 0; r < 4; ++r) {
            const int br = r * 64 + u;
            bias2[tt][r] = bih2[br] + bhh2[br];
        }
    }

    half8 a1x, a1h;
    float4v bias1;
    {
        const int m = w * 16 + n;
        const int row = (m & 3) * 32 + (m >> 2);
        #pragma unroll
        for (int j = 0; j < 8; ++j) {
            const int k = quad * 8 + j;
            a1x[j] = (_Float16)((k < FF) ? Wih1[row * FF + k] : 0.0f);
            a1h[j] = (_Float16)Whh1[row * H1 + k];
        }
        const int u1_ = w * 4 + quad;
        #pragma unroll
        for (int r = 0; r < 4; ++r) {
            const int br = r * 32 + u1_;
            bias1[r] = bih1[br] + bhh1[br];
        }
    }

    const int u1   = w * 4 + quad;
    const int offB = bfrag_off(u1, n);
    int off2[2];
    #pragma unroll
    for (int tt = 0; tt < 2; ++tt)
        off2[tt] = bfrag_off(32 + (2 * w + tt) * 4 + quad, n);

    const int b1q  = quad & 1;
    const int xrow = (row0 + n) * FF;
    const int xo0 = 8 * b1q;
    const int xo1 = 8 * b1q + 2;
    const int xo2 = 8 * b1q + 4;
    const int xo3 = 6 * b1q + 6;

    float c1r = 0.0f;
    float2 xr0[4], xr1[4];

    for (int z = l; z < 2 * 3 * 256; z += 512) ((unsigned*)s2f)[z] = 0u;

    {
        const float* xp = x + xrow;
        xr0[0] = *(const float2*)(xp + xo0);
        xr0[1] = *(const float2*)(xp + xo1);
        xr0[2] = *(const float2*)(xp + xo2);
        xr0[3] = *(const float2*)(xp + xo3);
        const float* xq = x + BB * FF + xrow;
        xr1[0] = *(const float2*)(xq + xo0);
        xr1[1] = *(const float2*)(xq + xo1);
        xr1[2] = *(const float2*)(xq + xo2);
        xr1[3] = *(const float2*)(xq + xo3);
    }
    __syncthreads();

#define LSTM_STEP_F(i_, CP_, RP_, XR_) do {                                        \
        const half8 tb0 = *(const half8*)(s2f[RP_] + lane * 4);                    \
        const half8 tb1 = *(const half8*)(s2f[RP_] + 256 + lane * 4);              \
        const half8 tb2 = *(const half8*)(s2f[RP_] + 512 + lane * 4);              \
        half8 xb;                                                                  \
        xb[0] = (_Float16)XR_[0].x; xb[1] = (_Float16)XR_[0].y;                    \
        xb[2] = (_Float16)XR_[1].x; xb[3] = (_Float16)XR_[1].y;                    \
        xb[4] = (_Float16)XR_[2].x; xb[5] = (_Float16)XR_[2].y;                    \
        xb[6] = (_Float16)XR_[3].x; xb[7] = (_Float16)XR_[3].y;                    \
        { int tn_ = (i_) + 2; if (tn_ > TT - 1) tn_ = TT - 1;                      \
          const float* xp_ = x + tn_ * (BB * FF) + xrow;                           \
          XR_[0] = *(const float2*)(xp_ + xo0);                                    \
          XR_[1] = *(const float2*)(xp_ + xo1);                                    \
          XR_[2] = *(const float2*)(xp_ + xo2);                                    \
          XR_[3] = *(const float2*)(xp_ + xo3); }                                  \
        if (l < 14) {                                                              \
            int tp_ = (i_) + 16; if (tp_ > TT - 1) tp_ = TT - 1;                   \
            __builtin_amdgcn_global_load_lds(                                      \
                (av1_t*)(x + (size_t)tp_ * (BB * FF) + row0 * FF + l * 16),        \
                (av3_t*)&pfl[0], 4, 0, 0);                                         \
        }                                                                          \
        float4v acc1 = mfma16(a1x, xb, bias1);                                     \
        acc1 = mfma16(a1h, tb0, acc1);                                             \
        const float cn1 = sigmoidf_(acc1[1]) * c1r                                 \
                        + sigmoidf_(acc1[0]) * tanhf_(acc1[2]);                    \
        c1r = cn1;                                                                 \
        ((_Float16*)s2f[CP_])[offB] = (_Float16)(sigmoidf_(acc1[3]) * tanhf_(cn1));\
        _Pragma("unroll")                                                          \
        for (int tt = 0; tt < 2; ++tt) {                                           \
            float4v acc = bias2[tt];                                               \
            acc = mfma16(a2[tt][0], tb0, acc);                                     \
            acc = mfma16(a2[tt][1], tb1, acc);                                     \
            acc = mfma16(a2[tt][2], tb2, acc);                                     \
            const float cn = sigmoidf_(acc[0]) * tanhf_(acc[2]);                   \
            const float h  = sigmoidf_(acc[3]) * tanhf_(cn);                       \
            ((_Float16*)s2f[CP_])[off2[tt]] = (_Float16)h;                         \
        }                                                                          \
        asm volatile("s_waitcnt lgkmcnt(0)" ::: "memory");                         \
        __builtin_amdgcn_s_barrier();                                              \
        asm volatile("" ::: "memory");                                             \
    } while (0)

    {
        half8 xb;
        xb[0] = (_Float16)xr0[0].x; xb[1] = (_Float16)xr0[0].y;
        xb[2] = (_Float16)xr0[1].x; xb[3] = (_Float16)xr0[1].y;
        xb[4] = (_Float16)xr0[2].x; xb[5] = (_Float16)xr0[2].y;
        xb[6] = (_Float16)xr0[3].x; xb[7] = (_Float16)xr0[3].y;
        {   const float* xp_ = x + 2 * (BB * FF) + xrow;
            xr0[0] = *(const float2*)(xp_ + xo0);
            xr0[1] = *(const float2*)(xp_ + xo1);
            xr0[2] = *(const float2*)(xp_ + xo2);
            xr0[3] = *(const float2*)(xp_ + xo3); }
        if (l < 14) {
            __builtin_amdgcn_global_load_lds(
                (av1_t*)(x + (size_t)16 * (BB * FF) + row0 * FF + l * 16),
                (av3_t*)&pfl[0], 4, 0, 0);
        }
        float4v acc1 = mfma16(a1x, xb, bias1);
        const float cn1 = sigmoidf_(acc1[0]) * tanhf_(acc1[2]);
        c1r = cn1;
        ((_Float16*)s2f[0])[offB] = (_Float16)(sigmoidf_(acc1[3]) * tanhf_(cn1));
        asm volatile("s_waitcnt lgkmcnt(0)" ::: "memory");
        __builtin_amdgcn_s_barrier();
        asm volatile("" ::: "memory");
    }

    #pragma unroll 1
    for (int ii = 0; ii < 255; ++ii) {
        const int i0 = 2 * ii + 1;
        LSTM_STEP_F(i0,     1, 0, xr1);
        LSTM_STEP_F(i0 + 1, 0, 1, xr0);
    }
    LSTM_STEP_F(511, 1, 0, xr1);

    {
        const half8 tb0 = *(const half8*)(s2f[1] + lane * 4);
        const half8 tb1 = *(const half8*)(s2f[1] + 256 + lane * 4);
        const half8 tb2 = *(const half8*)(s2f[1] + 512 + lane * 4);
        #pragma unroll
        for (int tt = 0; tt < 2; ++tt) {
            float4v acc = bias2[tt];
            acc = mfma16(a2[tt][0], tb0, acc);
            acc = mfma16(a2[tt][1], tb1, acc);
            acc = mfma16(a2[tt][2], tb2, acc);
            const float cn = sigmoidf_(acc[0]) * tanhf_(acc[2]);
            const float h  = sigmoidf_(acc[3]) * tanhf_(cn);
            h2plain[n][(2 * w + tt) * 4 + quad] = (_Float16)h;
        }
        __syncthreads();
    }

    if (l < NR * 8) {
        const int rr = l >> 3, j = l & 7;
        float a = bfc1[j];
        #pragma unroll
        for (int k = 0; k < H2; ++k)
            a = fmaf(fmaxf((float)h2plain[rr][k], 0.0f), Wfc1[j * H2 + k], a);
        mlp1[rr][j] = fmaxf(a, 0.0f);
    }
    __syncthreads();
    if (l < NR * 8) {
        const int rr = l >> 3, j = l & 7;
        float a = bfc2[j];
        #pragma unroll
        for (int k = 0; k < 8; ++k) a = fmaf(mlp1[rr][k], Wfc2[j * 8 + k], a);
        mlp2[rr][j] = fmaxf(a, 0.0f);
    }
    __syncthreads();
    if (l < NR) {
        float a = bfc[0];
        #pragma unroll
        for (int k = 0; k < 8; ++k) a = fmaf(mlp2[l][k], Wfc[k], a);
        out[row0 + l] = a;
    }
#undef LSTM_STEP_F
}

extern "C" void kernel_launch(void* const* d_in, const int* in_sizes, int n_in,
                              void* d_out, int out_size, void* d_ws, size_t ws_size,
                              hipStream_t stream) {
    const float* x    = (const float*)d_in[0];
    const float* Wih1 = (const float*)d_in[1];
    const float* Whh1 = (const float*)d_in[2];
    const float* bih1 = (const float*)d_in[3];
    const float* bhh1 = (const float*)d_in[4];
    const float* Wih2 = (const float*)d_in[5];
    const float* Whh2 = (const float*)d_in[6];
    const float* bih2 = (const float*)d_in[7];
    const float* bhh2 = (const float*)d_in[8];
    const float* Wfc1 = (const float*)d_in[9];
    const float* bfc1 = (const float*)d_in[10];
    const float* Wfc2 = (const float*)d_in[11];
    const float* bfc2 = (const float*)d_in[12];
    const float* Wfc  = (const float*)d_in[13];
    const float* bfc  = (const float*)d_in[14];
    float* out = (float*)d_out;

    const size_t xg_bytes = (size_t)TT * BB * (4 * H1) * sizeof(float);  // 134 MB
    if (d_ws != nullptr && ws_size >= xg_bytes) {
        float* xg = (float*)d_ws;
        xg_precompute<<<dim3(TT), dim3(512), 0, stream>>>(x, Wih1, bih1, bhh1, xg);
        lstm3_xg<<<dim3(NBLK), dim3(512), 0, stream>>>(
            xg, Wih2, Whh1, Whh2, bih2, bhh2,
            Wfc1, bfc1, Wfc2, bfc2, Wfc, bfc, out);
    } else {
        lstm3_kernel<<<dim3(NBLK), dim3(512), 0, stream>>>(
            x, Wih1, Whh1, bih1, bhh1, Wih2, Whh2, bih2, bhh2,
            Wfc1, bfc1, Wfc2, bfc2, Wfc, bfc, out);
    }
}